// Round 1
// baseline (1908.625 us; speedup 1.0000x reference)
//
#include <hip/hip_runtime.h>

#define NB 512
#define DK 256
#define DV 256
#define PP 2048
#define P4 (PP/4)          // 512 float4 per row
#define SCALE 0.0625f      // 1/sqrt(256)

__global__ __launch_bounds__(512, 2)
void attn_kernel(const float* __restrict__ Q,
                 const float* __restrict__ K,
                 const float* __restrict__ V,
                 const int*   __restrict__ mask,
                 float*       __restrict__ out)
{
    const int b    = blockIdx.x;
    const int tid  = threadIdx.x;      // 0..511
    const int lane = tid & 63;
    const int wave = tid >> 6;         // 0..7

    __shared__ float Qs[DK];
    __shared__ float attn[PP];
    __shared__ float red[8];

    // ---- stage Q[b,:] into LDS ----
    if (tid < DK) Qs[tid] = Q[(size_t)b * DK + tid];
    __syncthreads();

    // ---- phase 1: energy[p] = sum_d Q[d] * K[d][p], thread owns p4=tid ----
    const float4* __restrict__ K4 = (const float4*)(K + (size_t)b * DK * PP);
    float4 acc = make_float4(0.f, 0.f, 0.f, 0.f);
    #pragma unroll 8
    for (int d = 0; d < DK; ++d) {
        const float  q = Qs[d];
        const float4 k = K4[d * P4 + tid];
        acc.x = fmaf(q, k.x, acc.x);
        acc.y = fmaf(q, k.y, acc.y);
        acc.z = fmaf(q, k.z, acc.z);
        acc.w = fmaf(q, k.w, acc.w);
    }

    // multiplicative mask, then scale (masked slots score 0, still in softmax)
    const int4 m = ((const int4*)(mask + (size_t)b * PP))[tid];
    float4 sc;
    sc.x = acc.x * (float)m.x * SCALE;
    sc.y = acc.y * (float)m.y * SCALE;
    sc.z = acc.z * (float)m.z * SCALE;
    sc.w = acc.w * (float)m.w * SCALE;

    // ---- phase 2: softmax over P ----
    // block max
    float lmax = fmaxf(fmaxf(sc.x, sc.y), fmaxf(sc.z, sc.w));
    #pragma unroll
    for (int off = 1; off < 64; off <<= 1)
        lmax = fmaxf(lmax, __shfl_xor(lmax, off, 64));
    if (lane == 0) red[wave] = lmax;
    __syncthreads();
    float gmax = red[0];
    #pragma unroll
    for (int w = 1; w < 8; ++w) gmax = fmaxf(gmax, red[w]);
    __syncthreads();   // everyone done reading red before reuse

    float4 e;
    e.x = expf(sc.x - gmax);
    e.y = expf(sc.y - gmax);
    e.z = expf(sc.z - gmax);
    e.w = expf(sc.w - gmax);

    float lsum = e.x + e.y + e.z + e.w;
    #pragma unroll
    for (int off = 1; off < 64; off <<= 1)
        lsum += __shfl_xor(lsum, off, 64);
    if (lane == 0) red[wave] = lsum;
    __syncthreads();
    float gsum = 0.f;
    #pragma unroll
    for (int w = 0; w < 8; ++w) gsum += red[w];
    const float rinv = 1.0f / gsum;

    float4 a4;
    a4.x = e.x * rinv; a4.y = e.y * rinv; a4.z = e.z * rinv; a4.w = e.w * rinv;
    ((float4*)attn)[tid] = a4;
    __syncthreads();

    // ---- phase 3: out[v] = sum_p attn[p] * V[v][p] ----
    // hoist attn into registers: lane covers p4 = lane + 64*j, j=0..7
    const float4* __restrict__ A4 = (const float4*)attn;
    float4 areg[8];
    #pragma unroll
    for (int j = 0; j < 8; ++j) areg[j] = A4[lane + 64 * j];

    const float4* __restrict__ V4 = (const float4*)(V + (size_t)b * DV * PP);
    const int v0 = wave * 32;
    for (int v = v0; v < v0 + 32; ++v) {
        float4 a = make_float4(0.f, 0.f, 0.f, 0.f);
        #pragma unroll
        for (int j = 0; j < 8; ++j) {
            const float4 vv = V4[v * P4 + lane + 64 * j];
            a.x = fmaf(areg[j].x, vv.x, a.x);
            a.y = fmaf(areg[j].y, vv.y, a.y);
            a.z = fmaf(areg[j].z, vv.z, a.z);
            a.w = fmaf(areg[j].w, vv.w, a.w);
        }
        float s = (a.x + a.y) + (a.z + a.w);
        #pragma unroll
        for (int off = 1; off < 64; off <<= 1)
            s += __shfl_xor(s, off, 64);
        if (lane == 0) out[(size_t)b * DV + v] = s;
    }
}

extern "C" void kernel_launch(void* const* d_in, const int* in_sizes, int n_in,
                              void* d_out, int out_size, void* d_ws, size_t ws_size,
                              hipStream_t stream) {
    const float* Q    = (const float*)d_in[0];
    const float* K    = (const float*)d_in[1];
    const float* V    = (const float*)d_in[2];
    const int*   mask = (const int*)d_in[3];
    float*       out  = (float*)d_out;

    attn_kernel<<<NB, 512, 0, stream>>>(Q, K, V, mask, out);
}